// Round 1
// baseline (6916.872 us; speedup 1.0000x reference)
//
#include <hip/hip_runtime.h>
#include <float.h>
#include <math.h>

// ============================================================================
// BeamSearchDecoder — MI355X implementation.
//
// EQUIVALENCE PROOF (reference -> greedy): h0 = repeat(encoder_hidden, K) and
// scores0 = 0 make all K=3 beams of a batch identical. Then total[b,k,j] =
// scores[b,k] + next_scores[b,k,j] is identical across k, so the flattened 9
// candidates are [v0,v1,v2]x3 with v0>v1>v2 (ties measure-zero). The top-3 of
// that multiset is the three copies of v0 REGARDLESS of tie-break order, so
// tok_idx = top_idx % K == 0 for every selected beam: every beam appends the
// greedy argmax token and all beams remain identical. Induction => the whole
// decode is greedy argmax decoding; decoded = one-hot(greedy seq); h output =
// final greedy h replicated x3; scores = cumulative greedy logp replicated x3.
// score update per step: += max_logit - logsumexp = -log(sum exp(l - max)).
//
// All math is fp32 to match the numpy fp32 reference's argmax decisions
// (bf16 logits would flip near-ties in the one-hot output).
// ============================================================================

#define BB 32        // batch
#define HH 512       // hidden
#define EE 256       // embed
#define VV 32000     // vocab
#define G3H 1536     // 3*H
#define TSTEPS 32    // MAX_LENGTH
#define NCH 32       // vocab chunks for logits kernel
#define CHV 1000     // vocab entries per chunk
#define DEC_ELEMS (BB * (TSTEPS + 1) * VV)  // 33,792,000
#define H_ELEMS (BB * 3 * HH)               // 49,152

// ---------------------------------------------------------------------------
// Setup: transpose W_ih (1536,256)->(256,1536) and W_hh (1536,512)->(512,1536)
// ---------------------------------------------------------------------------
__global__ __launch_bounds__(256) void k_transpose_small(
    const float* __restrict__ W_ih, const float* __restrict__ W_hh,
    float* __restrict__ Wt_ih, float* __restrict__ Wt_hh) {
  int idx = blockIdx.x * 256 + threadIdx.x;  // total 1,179,648 = 4608*256
  if (idx < EE * G3H) {
    int k = idx / G3H, j = idx % G3H;
    Wt_ih[idx] = W_ih[j * EE + k];
  } else {
    int i2 = idx - EE * G3H;
    int k = i2 / G3H, j = i2 % G3H;
    Wt_hh[i2] = W_hh[j * HH + k];
  }
}

// ---------------------------------------------------------------------------
// Setup: tiled transpose W_out (V,H) -> Wt_out (H,V), 32x32 tiles via LDS
// ---------------------------------------------------------------------------
__global__ __launch_bounds__(256) void k_transpose_out(
    const float* __restrict__ W, float* __restrict__ Wt) {
  __shared__ float t[32][33];
  const int vb = blockIdx.x * 32;  // gridDim.x = 1000
  const int kb = blockIdx.y * 32;  // gridDim.y = 16
  const int c = threadIdx.x & 31, rq = threadIdx.x >> 5;  // 8 row-threads
#pragma unroll
  for (int i = 0; i < 4; ++i) {
    int r = rq + i * 8;
    t[r][c] = W[(size_t)(vb + r) * HH + kb + c];
  }
  __syncthreads();
#pragma unroll
  for (int i = 0; i < 4; ++i) {
    int r = rq + i * 8;
    Wt[(size_t)(kb + r) * VV + vb + c] = t[c][r];
  }
}

// ---------------------------------------------------------------------------
// Setup: h0 = encoder_hidden, scores = 0, seq[0][:] = START(=1)
// ---------------------------------------------------------------------------
__global__ __launch_bounds__(256) void k_init(
    const float* __restrict__ enc_h, float* __restrict__ hb0,
    float* __restrict__ scores, int* __restrict__ tok_seq) {
  int idx = blockIdx.x * 256 + threadIdx.x;  // grid 64*256 = 16384
  if (idx < BB * HH) hb0[idx] = enc_h[idx];
  if (idx < BB) { scores[idx] = 0.0f; tok_seq[idx] = 1; }
}

// ---------------------------------------------------------------------------
// Logits: per block (row-group rg of 4 rows, vocab chunk ch of 1000).
// acc[4 rows][4 v] over K=512; then per-(row,chunk) partials:
//   pm = chunk max, pidx = chunk argmax (lowest index wins), ps = sum exp(l-pm)
// ---------------------------------------------------------------------------
__global__ __launch_bounds__(256) void k_logits(
    const float* __restrict__ Wt,    // (H, V)
    const float* __restrict__ bout,  // (V)
    const float* __restrict__ hmat,  // (B, H) = h_new for this step
    float* __restrict__ pm, float* __restrict__ ps, int* __restrict__ pidx) {
  const int tid = threadIdx.x;
  const int rg = blockIdx.x >> 5;   // 0..7
  const int ch = blockIdx.x & 31;   // 0..31
  const int r0 = rg * 4;
  __shared__ float hsh[4 * HH];
  for (int i = tid; i < 4 * HH; i += 256) hsh[i] = hmat[r0 * HH + i];
  __syncthreads();

  const bool act = (tid < 250);     // 250*4 = 1000 vocab per chunk
  const int v0 = ch * CHV + tid * 4;
  float acc[4][4];
  if (act) {
    const float4 b4 = *(const float4*)(bout + v0);
#pragma unroll
    for (int r = 0; r < 4; ++r) {
      acc[r][0] = b4.x; acc[r][1] = b4.y; acc[r][2] = b4.z; acc[r][3] = b4.w;
    }
    const float* wp = Wt + v0;
    for (int k = 0; k < HH; k += 8) {
      float hv[4][8];
#pragma unroll
      for (int r = 0; r < 4; ++r) {
        const float4 a = *(const float4*)(hsh + r * HH + k);
        const float4 b = *(const float4*)(hsh + r * HH + k + 4);
        hv[r][0] = a.x; hv[r][1] = a.y; hv[r][2] = a.z; hv[r][3] = a.w;
        hv[r][4] = b.x; hv[r][5] = b.y; hv[r][6] = b.z; hv[r][7] = b.w;
      }
#pragma unroll
      for (int kk = 0; kk < 8; ++kk) {
        const float4 w = *(const float4*)(wp + (size_t)kk * VV);
#pragma unroll
        for (int r = 0; r < 4; ++r) {
          acc[r][0] = fmaf(hv[r][kk], w.x, acc[r][0]);
          acc[r][1] = fmaf(hv[r][kk], w.y, acc[r][1]);
          acc[r][2] = fmaf(hv[r][kk], w.z, acc[r][2]);
          acc[r][3] = fmaf(hv[r][kk], w.w, acc[r][3]);
        }
      }
      wp += 8 * VV;
    }
  }

  // per-thread max+argmax per row (ascending i => lowest index wins on ties)
  float mv[4]; int mi[4];
#pragma unroll
  for (int r = 0; r < 4; ++r) {
    mv[r] = -FLT_MAX; mi[r] = 0x7fffffff;
    if (act) {
#pragma unroll
      for (int i = 0; i < 4; ++i) {
        if (acc[r][i] > mv[r]) { mv[r] = acc[r][i]; mi[r] = v0 + i; }
      }
    }
  }
  // wave(64) all-reduce max+argmax
#pragma unroll
  for (int off = 1; off < 64; off <<= 1) {
#pragma unroll
    for (int r = 0; r < 4; ++r) {
      float om = __shfl_xor(mv[r], off);
      int oi = __shfl_xor(mi[r], off);
      if (om > mv[r] || (om == mv[r] && oi < mi[r])) { mv[r] = om; mi[r] = oi; }
    }
  }
  __shared__ float wm[4][4]; __shared__ int wi[4][4];
  __shared__ float bm[4]; __shared__ int bi[4];
  const int wv = tid >> 6, lane = tid & 63;
  if (lane == 0) {
#pragma unroll
    for (int r = 0; r < 4; ++r) { wm[wv][r] = mv[r]; wi[wv][r] = mi[r]; }
  }
  __syncthreads();
  if (tid < 4) {
    float m = wm[0][tid]; int ii = wi[0][tid];
#pragma unroll
    for (int w = 1; w < 4; ++w) {
      if (wm[w][tid] > m || (wm[w][tid] == m && wi[w][tid] < ii)) {
        m = wm[w][tid]; ii = wi[w][tid];
      }
    }
    bm[tid] = m; bi[tid] = ii;
  }
  __syncthreads();

  // sum exp(l - chunk_max) per row
  float sv[4] = {0.f, 0.f, 0.f, 0.f};
  if (act) {
#pragma unroll
    for (int r = 0; r < 4; ++r) {
#pragma unroll
      for (int i = 0; i < 4; ++i) sv[r] += expf(acc[r][i] - bm[r]);
    }
  }
#pragma unroll
  for (int off = 1; off < 64; off <<= 1) {
#pragma unroll
    for (int r = 0; r < 4; ++r) sv[r] += __shfl_xor(sv[r], off);
  }
  __shared__ float wsum[4][4];
  if (lane == 0) {
#pragma unroll
    for (int r = 0; r < 4; ++r) wsum[wv][r] = sv[r];
  }
  __syncthreads();
  if (tid < 4) {
    const int row = r0 + tid;
    pm[row * NCH + ch] = bm[tid];
    ps[row * NCH + ch] = wsum[0][tid] + wsum[1][tid] + wsum[2][tid] + wsum[3][tid];
    pidx[row * NCH + ch] = bi[tid];
  }
}

// ---------------------------------------------------------------------------
// Per-step kernel: one block per batch row, 1024 threads.
//  Phase A: select token from previous step's logits partials (step>=1);
//           step==0 uses START. step==32 does select only (no GRU).
//  Phase B: stage x = relu(emb[token]) and h_prev in LDS; zero accumulators.
//  Phase C: gi = x@W_ihT, gh = h@W_hhT via (128 j-quads x 8 k-slices),
//           LDS float atomics accumulate partial dots.
//  Phase D: GRU gate math -> h_new.
// ---------------------------------------------------------------------------
__global__ __launch_bounds__(1024) void k_step(
    const int step,
    const float* __restrict__ emb,
    const float* __restrict__ Wt_ih,  // (E, 1536)
    const float* __restrict__ Wt_hh,  // (H, 1536)
    const float* __restrict__ b_ih, const float* __restrict__ b_hh,
    const float* __restrict__ hin, float* __restrict__ hout,
    const float* __restrict__ pm, const float* __restrict__ ps,
    const int* __restrict__ pidx,
    float* __restrict__ scores, int* __restrict__ tok_seq) {
  const int row = blockIdx.x, tid = threadIdx.x;
  __shared__ float xs[EE];
  __shared__ float hs[HH];
  __shared__ float gsum[6 * HH];
  __shared__ int tok_sh;

  // ---- Phase A: token selection ----
  if (step == 0) {
    if (tid == 0) tok_sh = 1;  // START
  } else if (tid < 64) {
    const int c = tid;
    float m = (c < NCH) ? pm[row * NCH + c] : -FLT_MAX;
    float s = (c < NCH) ? ps[row * NCH + c] : 0.0f;
    int ix = (c < NCH) ? pidx[row * NCH + c] : 0x7fffffff;
    float gm = m; int gi = ix;
#pragma unroll
    for (int off = 1; off < 64; off <<= 1) {
      float om = __shfl_xor(gm, off);
      int oi = __shfl_xor(gi, off);
      if (om > gm || (om == gm && oi < gi)) { gm = om; gi = oi; }
    }
    float term = (c < NCH) ? s * expf(m - gm) : 0.0f;
#pragma unroll
    for (int off = 1; off < 64; off <<= 1) term += __shfl_xor(term, off);
    if (tid == 0) {
      tok_sh = gi;
      scores[row] -= logf(term);       // += max - logsumexp
      tok_seq[step * BB + row] = gi;   // seq slot = step (selection of step-1)
    }
  }
  __syncthreads();

  if (step < TSTEPS) {
    const int tok = tok_sh;
    // ---- Phase B ----
    for (int i = tid; i < 6 * HH; i += 1024) gsum[i] = 0.0f;
    if (tid < EE) {
      float e = emb[(size_t)tok * EE + tid];
      xs[tid] = e > 0.0f ? e : 0.0f;
    } else if (tid < EE + HH) {
      hs[tid - EE] = hin[row * HH + (tid - EE)];
    }
    __syncthreads();

    // ---- Phase C ----
    const int jq = tid & 127, kq = tid >> 7;  // 128 j-quads x 8 k-slices
    const int j0 = jq * 4;
    float4 gi0 = {0, 0, 0, 0}, gi1 = {0, 0, 0, 0}, gi2 = {0, 0, 0, 0};
    float4 gh0 = {0, 0, 0, 0}, gh1 = {0, 0, 0, 0}, gh2 = {0, 0, 0, 0};
    for (int k = kq * 32; k < kq * 32 + 32; ++k) {
      const float xk = xs[k];
      const float* wr = Wt_ih + k * G3H + j0;
      const float4 w0 = *(const float4*)(wr);
      const float4 w1 = *(const float4*)(wr + 512);
      const float4 w2 = *(const float4*)(wr + 1024);
      gi0.x = fmaf(xk, w0.x, gi0.x); gi0.y = fmaf(xk, w0.y, gi0.y);
      gi0.z = fmaf(xk, w0.z, gi0.z); gi0.w = fmaf(xk, w0.w, gi0.w);
      gi1.x = fmaf(xk, w1.x, gi1.x); gi1.y = fmaf(xk, w1.y, gi1.y);
      gi1.z = fmaf(xk, w1.z, gi1.z); gi1.w = fmaf(xk, w1.w, gi1.w);
      gi2.x = fmaf(xk, w2.x, gi2.x); gi2.y = fmaf(xk, w2.y, gi2.y);
      gi2.z = fmaf(xk, w2.z, gi2.z); gi2.w = fmaf(xk, w2.w, gi2.w);
    }
    for (int k = kq * 64; k < kq * 64 + 64; ++k) {
      const float hk = hs[k];
      const float* wr = Wt_hh + k * G3H + j0;
      const float4 w0 = *(const float4*)(wr);
      const float4 w1 = *(const float4*)(wr + 512);
      const float4 w2 = *(const float4*)(wr + 1024);
      gh0.x = fmaf(hk, w0.x, gh0.x); gh0.y = fmaf(hk, w0.y, gh0.y);
      gh0.z = fmaf(hk, w0.z, gh0.z); gh0.w = fmaf(hk, w0.w, gh0.w);
      gh1.x = fmaf(hk, w1.x, gh1.x); gh1.y = fmaf(hk, w1.y, gh1.y);
      gh1.z = fmaf(hk, w1.z, gh1.z); gh1.w = fmaf(hk, w1.w, gh1.w);
      gh2.x = fmaf(hk, w2.x, gh2.x); gh2.y = fmaf(hk, w2.y, gh2.y);
      gh2.z = fmaf(hk, w2.z, gh2.z); gh2.w = fmaf(hk, w2.w, gh2.w);
    }
    atomicAdd(&gsum[j0 + 0], gi0.x); atomicAdd(&gsum[j0 + 1], gi0.y);
    atomicAdd(&gsum[j0 + 2], gi0.z); atomicAdd(&gsum[j0 + 3], gi0.w);
    atomicAdd(&gsum[512 + j0 + 0], gi1.x); atomicAdd(&gsum[512 + j0 + 1], gi1.y);
    atomicAdd(&gsum[512 + j0 + 2], gi1.z); atomicAdd(&gsum[512 + j0 + 3], gi1.w);
    atomicAdd(&gsum[1024 + j0 + 0], gi2.x); atomicAdd(&gsum[1024 + j0 + 1], gi2.y);
    atomicAdd(&gsum[1024 + j0 + 2], gi2.z); atomicAdd(&gsum[1024 + j0 + 3], gi2.w);
    atomicAdd(&gsum[1536 + j0 + 0], gh0.x); atomicAdd(&gsum[1536 + j0 + 1], gh0.y);
    atomicAdd(&gsum[1536 + j0 + 2], gh0.z); atomicAdd(&gsum[1536 + j0 + 3], gh0.w);
    atomicAdd(&gsum[2048 + j0 + 0], gh1.x); atomicAdd(&gsum[2048 + j0 + 1], gh1.y);
    atomicAdd(&gsum[2048 + j0 + 2], gh1.z); atomicAdd(&gsum[2048 + j0 + 3], gh1.w);
    atomicAdd(&gsum[2560 + j0 + 0], gh2.x); atomicAdd(&gsum[2560 + j0 + 1], gh2.y);
    atomicAdd(&gsum[2560 + j0 + 2], gh2.z); atomicAdd(&gsum[2560 + j0 + 3], gh2.w);
    __syncthreads();

    // ---- Phase D ----
    if (tid < HH) {
      const int j = tid;
      const float ir = gsum[j] + b_ih[j];
      const float iz = gsum[512 + j] + b_ih[512 + j];
      const float in_ = gsum[1024 + j] + b_ih[1024 + j];
      const float hr = gsum[1536 + j] + b_hh[j];
      const float hz = gsum[2048 + j] + b_hh[512 + j];
      const float hn = gsum[2560 + j] + b_hh[1024 + j];
      const float r = 1.0f / (1.0f + expf(-(ir + hr)));
      const float z = 1.0f / (1.0f + expf(-(iz + hz)));
      const float n = tanhf(in_ + r * hn);
      hout[row * HH + j] = (1.0f - z) * n + z * hs[j];
    }
  }
}

// ---------------------------------------------------------------------------
// Epilogue: scatter one-hots, replicate h x3 and scores x3 into d_out.
// d_out already zeroed via hipMemsetAsync.
// ---------------------------------------------------------------------------
__global__ __launch_bounds__(256) void k_epilogue(
    const int* __restrict__ tok_seq, const float* __restrict__ hfin,
    const float* __restrict__ scores, float* __restrict__ out) {
  const int idx = blockIdx.x * 256 + threadIdx.x;
  if (idx < BB * (TSTEPS + 1)) {  // 1056 one-hot positions
    const int b = idx / (TSTEPS + 1), t = idx % (TSTEPS + 1);
    out[(size_t)b * ((TSTEPS + 1) * VV) + (size_t)t * VV + tok_seq[t * BB + b]] = 1.0f;
  } else if (idx < 1056 + H_ELEMS) {
    const int i = idx - 1056;
    const int b = i / (3 * HH), j = i % HH;
    out[DEC_ELEMS + i] = hfin[b * HH + j];
  } else if (idx < 1056 + H_ELEMS + BB * 3) {
    const int i = idx - 1056 - H_ELEMS;
    out[DEC_ELEMS + H_ELEMS + i] = scores[i / 3];
  }
}

// ---------------------------------------------------------------------------
extern "C" void kernel_launch(void* const* d_in, const int* in_sizes, int n_in,
                              void* d_out, int out_size, void* d_ws, size_t ws_size,
                              hipStream_t stream) {
  // inputs: 0 encoder_outputs (unused), 1 encoder_hidden, 2 emb, 3 W_ih,
  //         4 W_hh, 5 b_ih, 6 b_hh, 7 W_out, 8 b_out
  const float* enc_h = (const float*)d_in[1];
  const float* emb   = (const float*)d_in[2];
  const float* W_ih  = (const float*)d_in[3];
  const float* W_hh  = (const float*)d_in[4];
  const float* b_ih  = (const float*)d_in[5];
  const float* b_hh  = (const float*)d_in[6];
  const float* W_out = (const float*)d_in[7];
  const float* b_out = (const float*)d_in[8];
  float* out = (float*)d_out;

  // workspace layout (floats) — total ~70.4 MB
  float* ws = (float*)d_ws;
  float* Wt_out = ws;                      // 512*32000 = 16,384,000
  float* Wt_ih  = Wt_out + 16384000;       // 256*1536  = 393,216
  float* Wt_hh  = Wt_ih + 393216;          // 512*1536  = 786,432
  float* hb0    = Wt_hh + 786432;          // 16,384
  float* hb1    = hb0 + BB * HH;           // 16,384
  float* pm     = hb1 + BB * HH;           // 1,024
  float* ps     = pm + BB * NCH;           // 1,024
  float* scores = ps + BB * NCH;           // 32
  int*   pidx   = (int*)(scores + BB);     // 1,024
  int*   tok_seq = pidx + BB * NCH;        // 33*32 = 1,056

  hipMemsetAsync(d_out, 0, (size_t)out_size * sizeof(float), stream);
  k_transpose_small<<<4608, 256, 0, stream>>>(W_ih, W_hh, Wt_ih, Wt_hh);
  k_transpose_out<<<dim3(1000, 16), 256, 0, stream>>>(W_out, Wt_out);
  k_init<<<64, 256, 0, stream>>>(enc_h, hb0, scores, tok_seq);

  for (int t = 0; t < TSTEPS; ++t) {
    float* hin  = (t & 1) ? hb1 : hb0;
    float* hout = (t & 1) ? hb0 : hb1;
    k_step<<<BB, 1024, 0, stream>>>(t, emb, Wt_ih, Wt_hh, b_ih, b_hh,
                                    hin, hout, pm, ps, pidx, scores, tok_seq);
    k_logits<<<256, 256, 0, stream>>>(Wt_out, b_out, hout, pm, ps, pidx);
  }
  // final selection (writes seq[32] and last score term); GRU phases skipped
  k_step<<<BB, 1024, 0, stream>>>(TSTEPS, emb, Wt_ih, Wt_hh, b_ih, b_hh,
                                  hb0, hb1, pm, ps, pidx, scores, tok_seq);
  // final h lives in hb0 (t=31 wrote hout=hb0)
  k_epilogue<<<197, 256, 0, stream>>>(tok_seq, hb0, scores, out);
}

// Round 2
// 4708.182 us; speedup vs baseline: 1.4691x; 1.4691x over previous
//
#include <hip/hip_runtime.h>
#include <float.h>
#include <math.h>

// ============================================================================
// BeamSearchDecoder — MI355X. Greedy-equivalence proof: h0 = repeat(enc_h, K)
// and scores0 = 0 make all K=3 beams identical; total[b,k,j] is then identical
// across k, so the 9 candidates are [v0,v1,v2]x3 and top-3 = three copies of
// v0 regardless of tie-break => every beam takes the argmax token and beams
// stay identical forever. decoded = one-hot(greedy seq), h = final greedy h
// x3, scores = cumulative greedy logp x3 (+= max - logsumexp per step).
//
// All logits math fp32 (argmax decisions must match the fp32 numpy reference).
//
// R2 changes vs R1 (which passed at 6917 us):
//  - k_step (33 x 152 us, latency-bound: 32 blocks + 64-VGPR cap) replaced by
//    k_gru: 64 blocks x 256 thr, select fused in prologue, register accs.
//  - k_logits: 16-row reuse (131 MB/step L3 traffic, was 524 MB), 32 accs.
// ============================================================================

#define BB 32        // batch
#define HH 512       // hidden
#define EE 256       // embed
#define VV 32000     // vocab
#define G3H 1536     // 3*H
#define TSTEPS 32    // MAX_LENGTH
#define NVB 63       // vocab blocks of 512 (63rd is half)
#define DEC_ELEMS (BB * (TSTEPS + 1) * VV)  // 33,792,000
#define H_ELEMS (BB * 3 * HH)               // 49,152

// ---------------------------------------------------------------------------
// Setup: transpose W_ih (1536,256)->(256,1536) and W_hh (1536,512)->(512,1536)
// ---------------------------------------------------------------------------
__global__ __launch_bounds__(256) void k_transpose_small(
    const float* __restrict__ W_ih, const float* __restrict__ W_hh,
    float* __restrict__ Wt_ih, float* __restrict__ Wt_hh) {
  int idx = blockIdx.x * 256 + threadIdx.x;  // total 1,179,648 = 4608*256
  if (idx < EE * G3H) {
    int k = idx / G3H, j = idx % G3H;
    Wt_ih[idx] = W_ih[j * EE + k];
  } else {
    int i2 = idx - EE * G3H;
    int k = i2 / G3H, j = i2 % G3H;
    Wt_hh[i2] = W_hh[j * HH + k];
  }
}

// ---------------------------------------------------------------------------
// Setup: tiled transpose W_out (V,H) -> Wt_out (H,V)
// ---------------------------------------------------------------------------
__global__ __launch_bounds__(256) void k_transpose_out(
    const float* __restrict__ W, float* __restrict__ Wt) {
  __shared__ float t[32][33];
  const int vb = blockIdx.x * 32;  // gridDim.x = 1000
  const int kb = blockIdx.y * 32;  // gridDim.y = 16
  const int c = threadIdx.x & 31, rq = threadIdx.x >> 5;
#pragma unroll
  for (int i = 0; i < 4; ++i) {
    int r = rq + i * 8;
    t[r][c] = W[(size_t)(vb + r) * HH + kb + c];
  }
  __syncthreads();
#pragma unroll
  for (int i = 0; i < 4; ++i) {
    int r = rq + i * 8;
    Wt[(size_t)(kb + r) * VV + vb + c] = t[c][r];
  }
}

// ---------------------------------------------------------------------------
// Setup: h0 = encoder_hidden, scores = 0, seq col 0 = START(=1)
// ---------------------------------------------------------------------------
__global__ __launch_bounds__(256) void k_init(
    const float* __restrict__ enc_h, float* __restrict__ hb0,
    float* __restrict__ scores, int* __restrict__ tok_seq) {
  int idx = blockIdx.x * 256 + threadIdx.x;  // 64*256 = 16384
  if (idx < BB * HH) hb0[idx] = enc_h[idx];
  if (idx < BB) { scores[idx] = 0.0f; tok_seq[idx] = 1; }
}

// ---------------------------------------------------------------------------
// GRU step with fused token-select prologue.
// Grid: 64 blocks = (rowgroup rg 0..7 of 4 rows) x (jtile jt 0..7 of 64 cols).
// Select: each wave reduces 63 chunk-partials for one row (done redundantly
// in every block; block jt==0 writes scores/tok_seq).
// Dot: thread = (jh lane 0..63, k-slice kq 0..3); 24 register accumulators
// (6 gate-cols x 4 rows); LDS reduce over k-slices; gate math; h_new write.
// step==TSTEPS: select only.
// ---------------------------------------------------------------------------
__global__ __launch_bounds__(256) void k_gru(
    const int step,
    const float* __restrict__ emb,
    const float* __restrict__ Wt_ih,  // (E, 1536)
    const float* __restrict__ Wt_hh,  // (H, 1536)
    const float* __restrict__ b_ih, const float* __restrict__ b_hh,
    const float* __restrict__ hin, float* __restrict__ hout,
    const float* __restrict__ pm, const float* __restrict__ ps,
    const int* __restrict__ pidx,
    float* __restrict__ scores, int* __restrict__ tok_seq) {
  const int tid = threadIdx.x;
  const int rg = blockIdx.x >> 3;   // 0..7
  const int jt = blockIdx.x & 7;    // 0..7
  const int r0 = rg * 4, j0 = jt * 64;
  const int lane = tid & 63, kq = tid >> 6;

  __shared__ int toks[4];
  __shared__ float xs[4][EE];
  __shared__ float hs[4][HH];
  __shared__ float gpart[256 * 25];  // stride 25: conflict-free

  // ---- select (token for this step's GRU input / this step's seq column) --
  if (step == 0) {
    if (tid < 4) toks[tid] = 1;  // START
  } else {
    const int r = kq;            // wave r handles row r0+r
    const int row = r0 + r;
    const bool cv = (lane < NVB);
    float m = cv ? pm[row * 64 + lane] : -FLT_MAX;
    float s = cv ? ps[row * 64 + lane] : 0.0f;
    int ix = cv ? pidx[row * 64 + lane] : 0x7fffffff;
    float gm = m; int gi = ix;
#pragma unroll
    for (int off = 1; off < 64; off <<= 1) {
      float om = __shfl_xor(gm, off);
      int oi = __shfl_xor(gi, off);
      if (om > gm || (om == gm && oi < gi)) { gm = om; gi = oi; }
    }
    float term = cv ? s * __expf(m - gm) : 0.0f;
#pragma unroll
    for (int off = 1; off < 64; off <<= 1) term += __shfl_xor(term, off);
    if (lane == 0) {
      toks[r] = gi;
      if (jt == 0) {
        scores[row] -= logf(term);      // += max - logsumexp
        tok_seq[step * BB + row] = gi;  // seq column `step`
      }
    }
  }
  __syncthreads();
  if (step == TSTEPS) return;  // final call: selection only

  // ---- stage x = relu(emb[tok]) and h_prev ----
  for (int i = tid; i < 4 * EE; i += 256) {
    const int r = i >> 8, c = i & (EE - 1);
    const float e = emb[(size_t)toks[r] * EE + c];
    xs[r][c] = e > 0.0f ? e : 0.0f;
  }
  for (int i = tid; i < 4 * HH; i += 256) {
    const int r = i >> 9, c = i & (HH - 1);
    hs[r][c] = hin[(r0 + r) * HH + c];
  }
  __syncthreads();

  // ---- partial dots: thread covers k-slice kq for gate-cols {j,j+512,j+1024}
  float ai0[4] = {0, 0, 0, 0}, ai1[4] = {0, 0, 0, 0}, ai2[4] = {0, 0, 0, 0};
  float ah0[4] = {0, 0, 0, 0}, ah1[4] = {0, 0, 0, 0}, ah2[4] = {0, 0, 0, 0};
  {
    const float* wip = Wt_ih + j0 + lane;
    const int kend = kq * 64 + 64;
    for (int k = kq * 64; k < kend; k += 4) {
      float xk[4][4];
#pragma unroll
      for (int r = 0; r < 4; ++r) {
        const float4 t = *(const float4*)&xs[r][k];
        xk[r][0] = t.x; xk[r][1] = t.y; xk[r][2] = t.z; xk[r][3] = t.w;
      }
#pragma unroll
      for (int kk = 0; kk < 4; ++kk) {
        const float* wr = wip + (size_t)(k + kk) * G3H;
        const float w0 = wr[0], w1 = wr[512], w2 = wr[1024];
#pragma unroll
        for (int r = 0; r < 4; ++r) {
          ai0[r] = fmaf(w0, xk[r][kk], ai0[r]);
          ai1[r] = fmaf(w1, xk[r][kk], ai1[r]);
          ai2[r] = fmaf(w2, xk[r][kk], ai2[r]);
        }
      }
    }
  }
  {
    const float* whp = Wt_hh + j0 + lane;
    const int kend = kq * 128 + 128;
    for (int k = kq * 128; k < kend; k += 4) {
      float hk[4][4];
#pragma unroll
      for (int r = 0; r < 4; ++r) {
        const float4 t = *(const float4*)&hs[r][k];
        hk[r][0] = t.x; hk[r][1] = t.y; hk[r][2] = t.z; hk[r][3] = t.w;
      }
#pragma unroll
      for (int kk = 0; kk < 4; ++kk) {
        const float* wr = whp + (size_t)(k + kk) * G3H;
        const float w0 = wr[0], w1 = wr[512], w2 = wr[1024];
#pragma unroll
        for (int r = 0; r < 4; ++r) {
          ah0[r] = fmaf(w0, hk[r][kk], ah0[r]);
          ah1[r] = fmaf(w1, hk[r][kk], ah1[r]);
          ah2[r] = fmaf(w2, hk[r][kk], ah2[r]);
        }
      }
    }
  }
  {
    float* gp = gpart + tid * 25;
#pragma unroll
    for (int r = 0; r < 4; ++r) {
      gp[0 * 4 + r] = ai0[r]; gp[1 * 4 + r] = ai1[r]; gp[2 * 4 + r] = ai2[r];
      gp[3 * 4 + r] = ah0[r]; gp[4 * 4 + r] = ah1[r]; gp[5 * 4 + r] = ah2[r];
    }
  }
  __syncthreads();

  // ---- reduce k-slices + gate math: thread = (r = tid>>6, jh = lane) ----
  {
    const int r = tid >> 6, jh = tid & 63;
    float g[6];
#pragma unroll
    for (int c = 0; c < 6; ++c) {
      float s = 0.0f;
#pragma unroll
      for (int q = 0; q < 4; ++q) s += gpart[(q * 64 + jh) * 25 + c * 4 + r];
      g[c] = s;
    }
    const int j = j0 + jh;
    const float ir = g[0] + b_ih[j];
    const float iz = g[1] + b_ih[512 + j];
    const float in_ = g[2] + b_ih[1024 + j];
    const float hr = g[3] + b_hh[j];
    const float hz = g[4] + b_hh[512 + j];
    const float hn = g[5] + b_hh[1024 + j];
    const float rr = 1.0f / (1.0f + expf(-(ir + hr)));
    const float zz = 1.0f / (1.0f + expf(-(iz + hz)));
    const float nn = tanhf(in_ + rr * hn);
    hout[(r0 + r) * HH + j] = (1.0f - zz) * nn + zz * hs[r][j];
  }
}

// ---------------------------------------------------------------------------
// Logits + per-(row, vblock) softmax partials.
// Grid: (vb 0..62 of 512 vocab, rg 0..1 of 16 rows). Block 256 thr.
// Thread: vocab cols v0 = vb*512+tid and v1 = v0+256; 32 accumulators
// (16 rows x 2 v). h staged in 32 KB LDS, b128 broadcast reads.
// Emits per (row, vb): chunk max, argmax (lowest idx), sum exp(l - max).
// ---------------------------------------------------------------------------
__global__ __launch_bounds__(256) void k_logits(
    const float* __restrict__ Wt,    // (H, V)
    const float* __restrict__ bout,  // (V)
    const float* __restrict__ hmat,  // (B, H)
    float* __restrict__ pm, float* __restrict__ ps, int* __restrict__ pidx) {
  const int tid = threadIdx.x;
  const int vb = blockIdx.x;   // 0..62
  const int rg = blockIdx.y;   // 0..1
  const int r0 = rg * 16;
  __shared__ float hs[16 * HH];  // 32 KB
  {
    const float4* hp = (const float4*)(hmat + r0 * HH);
    float4* hd = (float4*)hs;
    for (int i = tid; i < 16 * HH / 4; i += 256) hd[i] = hp[i];
  }
  __syncthreads();

  const int v0 = vb * 512 + tid;
  const int v1 = v0 + 256;
  const bool ok1 = (v1 < VV);  // vb==62: second half OOB
  float acc0[16], acc1[16];
  {
    const float b0 = bout[v0];
    const float b1 = ok1 ? bout[v1] : 0.0f;
#pragma unroll
    for (int r = 0; r < 16; ++r) { acc0[r] = b0; acc1[r] = b1; }
  }
  const float* w0p = Wt + v0;
  const float* w1p = Wt + (ok1 ? v1 : v0);
  for (int k = 0; k < HH; k += 4) {
    float wa[4], wb[4];
#pragma unroll
    for (int kk = 0; kk < 4; ++kk) {
      wa[kk] = w0p[(size_t)(k + kk) * VV];
      wb[kk] = w1p[(size_t)(k + kk) * VV];
    }
#pragma unroll
    for (int r = 0; r < 16; ++r) {
      const float4 h4 = *(const float4*)&hs[r * HH + k];
      acc0[r] = fmaf(h4.x, wa[0], acc0[r]);
      acc0[r] = fmaf(h4.y, wa[1], acc0[r]);
      acc0[r] = fmaf(h4.z, wa[2], acc0[r]);
      acc0[r] = fmaf(h4.w, wa[3], acc0[r]);
      acc1[r] = fmaf(h4.x, wb[0], acc1[r]);
      acc1[r] = fmaf(h4.y, wb[1], acc1[r]);
      acc1[r] = fmaf(h4.z, wb[2], acc1[r]);
      acc1[r] = fmaf(h4.w, wb[3], acc1[r]);
    }
  }

  // ---- block reduce: max/argmax then sum-exp, per row ----
  float tm[16]; int ti[16];
#pragma unroll
  for (int r = 0; r < 16; ++r) {
    tm[r] = acc0[r]; ti[r] = v0;
    if (ok1 && acc1[r] > tm[r]) { tm[r] = acc1[r]; ti[r] = v1; }
  }
#pragma unroll
  for (int off = 1; off < 64; off <<= 1) {
#pragma unroll
    for (int r = 0; r < 16; ++r) {
      const float om = __shfl_xor(tm[r], off);
      const int oi = __shfl_xor(ti[r], off);
      if (om > tm[r] || (om == tm[r] && oi < ti[r])) { tm[r] = om; ti[r] = oi; }
    }
  }
  __shared__ float wm[4][16]; __shared__ int wi2[4][16];
  __shared__ float bm[16]; __shared__ int bi[16];
  __shared__ float wsums[4][16];
  const int wv = tid >> 6, lane = tid & 63;
  if (lane == 0) {
#pragma unroll
    for (int r = 0; r < 16; ++r) { wm[wv][r] = tm[r]; wi2[wv][r] = ti[r]; }
  }
  __syncthreads();
  if (tid < 16) {
    float m = wm[0][tid]; int ii = wi2[0][tid];
#pragma unroll
    for (int w = 1; w < 4; ++w) {
      if (wm[w][tid] > m || (wm[w][tid] == m && wi2[w][tid] < ii)) {
        m = wm[w][tid]; ii = wi2[w][tid];
      }
    }
    bm[tid] = m; bi[tid] = ii;
  }
  __syncthreads();
  float sv[16];
#pragma unroll
  for (int r = 0; r < 16; ++r) {
    sv[r] = __expf(acc0[r] - bm[r]) + (ok1 ? __expf(acc1[r] - bm[r]) : 0.0f);
  }
#pragma unroll
  for (int off = 1; off < 64; off <<= 1) {
#pragma unroll
    for (int r = 0; r < 16; ++r) sv[r] += __shfl_xor(sv[r], off);
  }
  if (lane == 0) {
#pragma unroll
    for (int r = 0; r < 16; ++r) wsums[wv][r] = sv[r];
  }
  __syncthreads();
  if (tid < 16) {
    const int row = r0 + tid;
    pm[row * 64 + vb] = bm[tid];
    ps[row * 64 + vb] = wsums[0][tid] + wsums[1][tid] + wsums[2][tid] + wsums[3][tid];
    pidx[row * 64 + vb] = bi[tid];
  }
}

// ---------------------------------------------------------------------------
// Epilogue: scatter one-hots, replicate h x3 and scores x3.
// ---------------------------------------------------------------------------
__global__ __launch_bounds__(256) void k_epilogue(
    const int* __restrict__ tok_seq, const float* __restrict__ hfin,
    const float* __restrict__ scores, float* __restrict__ out) {
  const int idx = blockIdx.x * 256 + threadIdx.x;
  if (idx < BB * (TSTEPS + 1)) {  // 1056 one-hot positions
    const int b = idx / (TSTEPS + 1), t = idx % (TSTEPS + 1);
    out[(size_t)b * ((TSTEPS + 1) * VV) + (size_t)t * VV + tok_seq[t * BB + b]] = 1.0f;
  } else if (idx < 1056 + H_ELEMS) {
    const int i = idx - 1056;
    const int b = i / (3 * HH), j = i % HH;
    out[DEC_ELEMS + i] = hfin[b * HH + j];
  } else if (idx < 1056 + H_ELEMS + BB * 3) {
    const int i = idx - 1056 - H_ELEMS;
    out[DEC_ELEMS + H_ELEMS + i] = scores[i / 3];
  }
}

// ---------------------------------------------------------------------------
extern "C" void kernel_launch(void* const* d_in, const int* in_sizes, int n_in,
                              void* d_out, int out_size, void* d_ws, size_t ws_size,
                              hipStream_t stream) {
  const float* enc_h = (const float*)d_in[1];
  const float* emb   = (const float*)d_in[2];
  const float* W_ih  = (const float*)d_in[3];
  const float* W_hh  = (const float*)d_in[4];
  const float* b_ih  = (const float*)d_in[5];
  const float* b_hh  = (const float*)d_in[6];
  const float* W_out = (const float*)d_in[7];
  const float* b_out = (const float*)d_in[8];
  float* out = (float*)d_out;

  // workspace layout (floats) — ~70.4 MB
  float* ws = (float*)d_ws;
  float* Wt_out = ws;                      // 512*32000
  float* Wt_ih  = Wt_out + 16384000;       // 256*1536
  float* Wt_hh  = Wt_ih + 393216;          // 512*1536
  float* hb0    = Wt_hh + 786432;          // 16,384
  float* hb1    = hb0 + BB * HH;           // 16,384
  float* pm     = hb1 + BB * HH;           // 32*64
  float* ps     = pm + BB * 64;            // 32*64
  float* scores = ps + BB * 64;            // 32
  int*   pidx   = (int*)(scores + BB);     // 32*64
  int*   tok_seq = pidx + BB * 64;         // 33*32

  hipMemsetAsync(d_out, 0, (size_t)out_size * sizeof(float), stream);
  k_transpose_small<<<4608, 256, 0, stream>>>(W_ih, W_hh, Wt_ih, Wt_hh);
  k_transpose_out<<<dim3(1000, 16), 256, 0, stream>>>(W_out, Wt_out);
  k_init<<<64, 256, 0, stream>>>(enc_h, hb0, scores, tok_seq);

  for (int t = 0; t < TSTEPS; ++t) {
    float* hin  = (t & 1) ? hb1 : hb0;
    float* hout = (t & 1) ? hb0 : hb1;
    k_gru<<<64, 256, 0, stream>>>(t, emb, Wt_ih, Wt_hh, b_ih, b_hh,
                                  hin, hout, pm, ps, pidx, scores, tok_seq);
    k_logits<<<dim3(NVB, 2), 256, 0, stream>>>(Wt_out, b_out, hout, pm, ps, pidx);
  }
  // final selection: writes seq col 32 + last score term, then returns
  k_gru<<<64, 256, 0, stream>>>(TSTEPS, emb, Wt_ih, Wt_hh, b_ih, b_hh,
                                hb0, hb1, pm, ps, pidx, scores, tok_seq);
  // final h lives in hb0 (t=31 odd: hout=hb0)
  k_epilogue<<<197, 256, 0, stream>>>(tok_seq, hb0, scores, out);
}

// Round 3
// 2668.758 us; speedup vs baseline: 2.5918x; 1.7642x over previous
//
#include <hip/hip_runtime.h>
#include <float.h>
#include <math.h>

// ============================================================================
// BeamSearchDecoder — MI355X. Greedy-equivalence: h0 = repeat(enc_h,K) and
// scores0 = 0 make all K=3 beams identical; the 9 candidates per batch are
// [v0,v1,v2]x3 and top-3 = three copies of v0 regardless of tie-break, so
// every beam takes the argmax token forever. decoded = one-hot(greedy seq),
// h = final greedy h x3, scores = cumulative (max - logsumexp) x3.
//
// All logits math fp32 (argmax decisions must track the fp32 numpy ref).
//
// R3 vs R2 (4708 us): k_logits was 120 us/step, latency-starved (126 blocks,
// VALUBusy 11%, 550 GB/s). Now: split-K GEMV (252 blocks, 64 reg accs,
// W read once) + combine kernel; k_gru 64->128 blocks, reads W_ih/W_hh in
// native layout (transpose-small kernel removed).
// ============================================================================

#define BB 32
#define HH 512
#define EE 256
#define VV 32000
#define TSTEPS 32
#define NCHK 32                              // combine chunks per row (1024 cols)
#define DEC_ELEMS (BB * (TSTEPS + 1) * VV)   // 33,792,000
#define H_ELEMS (BB * 3 * HH)                // 49,152

// ---------------------------------------------------------------------------
// Setup: tiled transpose W_out (V,H) -> Wt_out (H,V)
// ---------------------------------------------------------------------------
__global__ __launch_bounds__(256) void k_transpose_out(
    const float* __restrict__ W, float* __restrict__ Wt) {
  __shared__ float t[32][33];
  const int vb = blockIdx.x * 32;  // 1000
  const int kb = blockIdx.y * 32;  // 16
  const int c = threadIdx.x & 31, rq = threadIdx.x >> 5;
#pragma unroll
  for (int i = 0; i < 4; ++i) {
    int r = rq + i * 8;
    t[r][c] = W[(size_t)(vb + r) * HH + kb + c];
  }
  __syncthreads();
#pragma unroll
  for (int i = 0; i < 4; ++i) {
    int r = rq + i * 8;
    Wt[(size_t)(kb + r) * VV + vb + c] = t[c][r];
  }
}

// ---------------------------------------------------------------------------
// Setup: h0 = encoder_hidden, scores = 0, seq col 0 = START(=1)
// ---------------------------------------------------------------------------
__global__ __launch_bounds__(256) void k_init(
    const float* __restrict__ enc_h, float* __restrict__ hb0,
    float* __restrict__ scores, int* __restrict__ tok_seq) {
  int idx = blockIdx.x * 256 + threadIdx.x;  // 64*256
  if (idx < BB * HH) hb0[idx] = enc_h[idx];
  if (idx < BB) { scores[idx] = 0.0f; tok_seq[idx] = 1; }
}

// ---------------------------------------------------------------------------
// Split-K logits GEMV. Grid (63 vb, nkc kc). Block 256 thr.
// Thread: cols v0 = vb*512+tid, v1 = v0+256; 32-row reg accumulators each.
// h k-chunk staged in dynamic LDS (broadcast b128 reads). Writes fp32
// partial dot sums lpart[kc][row][v].  KLEN = 512/nkc.
// ---------------------------------------------------------------------------
__global__ __launch_bounds__(256) void k_gemv(
    const float* __restrict__ Wt,    // (H, V)
    const float* __restrict__ hmat,  // (B, H)
    float* __restrict__ lpart,       // (nkc, B, V)
    const int klen) {
  extern __shared__ float hs[];      // 32 * klen floats
  const int tid = threadIdx.x;
  const int vb = blockIdx.x;         // 0..62
  const int kc = blockIdx.y;
  // stage h chunk: rows 0..31, k in [kc*klen, kc*klen+klen)
  {
    const int nv = (32 * klen) >> 2;       // float4 count
    const int kq4 = klen >> 2;             // float4 per row
    float4* hd = (float4*)hs;
    const float4* hp = (const float4*)hmat;
    for (int i = tid; i < nv; i += 256) {
      const int row = i / kq4, off = i % kq4;
      hd[i] = hp[row * (HH >> 2) + kc * kq4 + off];
    }
  }
  __syncthreads();

  const int v0 = vb * 512 + tid;           // always < VV
  const int v1 = v0 + 256;
  const bool ok1 = (v1 < VV);
  float acc0[32], acc1[32];
#pragma unroll
  for (int r = 0; r < 32; ++r) { acc0[r] = 0.0f; acc1[r] = 0.0f; }

  const float* w0p = Wt + (size_t)kc * klen * VV + v0;
  const float* w1p = ok1 ? (w0p + 256) : w0p;
  const int nq = klen >> 2;
#pragma unroll 2
  for (int kq = 0; kq < nq; ++kq) {
    float a0[4], a1[4];
#pragma unroll
    for (int kk = 0; kk < 4; ++kk) {
      a0[kk] = w0p[(size_t)kk * VV];
      a1[kk] = w1p[(size_t)kk * VV];
    }
    w0p += (size_t)4 * VV;
    w1p += (size_t)4 * VV;
    const float* hq = hs + kq * 4;
#pragma unroll
    for (int r = 0; r < 32; ++r) {
      const float4 h4 = *(const float4*)(hq + r * klen);
      acc0[r] = fmaf(h4.x, a0[0], acc0[r]);
      acc0[r] = fmaf(h4.y, a0[1], acc0[r]);
      acc0[r] = fmaf(h4.z, a0[2], acc0[r]);
      acc0[r] = fmaf(h4.w, a0[3], acc0[r]);
      acc1[r] = fmaf(h4.x, a1[0], acc1[r]);
      acc1[r] = fmaf(h4.y, a1[1], acc1[r]);
      acc1[r] = fmaf(h4.z, a1[2], acc1[r]);
      acc1[r] = fmaf(h4.w, a1[3], acc1[r]);
    }
  }

  float* lp = lpart + (size_t)kc * BB * VV;
#pragma unroll
  for (int r = 0; r < 32; ++r) {
    lp[(size_t)r * VV + v0] = acc0[r];
    if (ok1) lp[(size_t)r * VV + v1] = acc1[r];
  }
}

// ---------------------------------------------------------------------------
// Combine: logits = sum_kc lpart + bias; per (row, chunk-of-1024) emit
// max / argmax (lowest idx) / sum exp(l - max).
// Grid (NCHK, 32 rows). Block 256 thr; thread = 4 cols (float4).
// ---------------------------------------------------------------------------
__global__ __launch_bounds__(256) void k_combine(
    const float* __restrict__ lpart, const float* __restrict__ bout,
    float* __restrict__ pm, float* __restrict__ ps, int* __restrict__ pidx,
    const int nkc) {
  const int tid = threadIdx.x;
  const int cx = blockIdx.x;   // 0..31
  const int row = blockIdx.y;  // 0..31
  const int c0 = cx * 1024 + tid * 4;
  const bool act = (c0 < VV);

  float l[4];
  float tm = -FLT_MAX; int ti = 0x7fffffff;
  if (act) {
    const float4 b4 = *(const float4*)(bout + c0);
    l[0] = b4.x; l[1] = b4.y; l[2] = b4.z; l[3] = b4.w;
    for (int kc = 0; kc < nkc; ++kc) {
      const float4 p4 = *(const float4*)(lpart + ((size_t)kc * BB + row) * VV + c0);
      l[0] += p4.x; l[1] += p4.y; l[2] += p4.z; l[3] += p4.w;
    }
#pragma unroll
    for (int i = 0; i < 4; ++i) {
      if (l[i] > tm) { tm = l[i]; ti = c0 + i; }
    }
  }
  // wave + block max/argmax
#pragma unroll
  for (int off = 1; off < 64; off <<= 1) {
    const float om = __shfl_xor(tm, off);
    const int oi = __shfl_xor(ti, off);
    if (om > tm || (om == tm && oi < ti)) { tm = om; ti = oi; }
  }
  __shared__ float wm[4]; __shared__ int wi[4];
  __shared__ float bm_s; __shared__ int bi_s;
  __shared__ float wsum[4];
  const int wv = tid >> 6, lane = tid & 63;
  if (lane == 0) { wm[wv] = tm; wi[wv] = ti; }
  __syncthreads();
  if (tid == 0) {
    float m = wm[0]; int ii = wi[0];
#pragma unroll
    for (int w = 1; w < 4; ++w) {
      if (wm[w] > m || (wm[w] == m && wi[w] < ii)) { m = wm[w]; ii = wi[w]; }
    }
    bm_s = m; bi_s = ii;
  }
  __syncthreads();
  const float bm = bm_s;
  float sv = 0.0f;
  if (act) {
#pragma unroll
    for (int i = 0; i < 4; ++i) sv += __expf(l[i] - bm);
  }
#pragma unroll
  for (int off = 1; off < 64; off <<= 1) sv += __shfl_xor(sv, off);
  if (lane == 0) wsum[wv] = sv;
  __syncthreads();
  if (tid == 0) {
    pm[row * NCHK + cx] = bm;
    ps[row * NCHK + cx] = wsum[0] + wsum[1] + wsum[2] + wsum[3];
    pidx[row * NCHK + cx] = bi_s;
  }
}

// ---------------------------------------------------------------------------
// GRU step with fused token-select prologue. Grid 128 = (rg 0..7 of 4 rows) x
// (jt 0..15 of 32 H-cols). Block 256 thr.
// Select: wave wv handles row r0+wv, reducing 32 chunk-partials; jt==0 blocks
// write scores/tok_seq. Dots read W_ih/W_hh in NATIVE layout (per-lane
// contiguous float4 over k). Thread = (jh 0..31, kq 0..7 k-slices), 24 accs,
// LDS reduce (stride-34 swizzle => 2-way conflicts only). step==TSTEPS:
// select only.
// ---------------------------------------------------------------------------
__global__ __launch_bounds__(256) void k_gru(
    const int step,
    const float* __restrict__ emb,
    const float* __restrict__ W_ih,   // (1536, 256) native
    const float* __restrict__ W_hh,   // (1536, 512) native
    const float* __restrict__ b_ih, const float* __restrict__ b_hh,
    const float* __restrict__ hin, float* __restrict__ hout,
    const float* __restrict__ pm, const float* __restrict__ ps,
    const int* __restrict__ pidx,
    float* __restrict__ scores, int* __restrict__ tok_seq) {
  const int tid = threadIdx.x;
  const int rg = blockIdx.x >> 4;   // 0..7
  const int jt = blockIdx.x & 15;   // 0..15
  const int r0 = rg * 4, j0 = jt * 32;
  const int lane = tid & 63, wv = tid >> 6;  // wv 0..3

  __shared__ int toks[4];
  __shared__ float xs[4][EE];
  __shared__ float hsm[4][HH];
  __shared__ float gpart[24 * 272];

  // ---- select ----
  if (step == 0) {
    if (tid < 4) toks[tid] = 1;  // START
  } else {
    const int row = r0 + wv;
    const bool cv = (lane < NCHK);
    float m = cv ? pm[row * NCHK + lane] : -FLT_MAX;
    float s = cv ? ps[row * NCHK + lane] : 0.0f;
    int ix = cv ? pidx[row * NCHK + lane] : 0x7fffffff;
    float gm = m; int gi = ix;
#pragma unroll
    for (int off = 1; off < 64; off <<= 1) {
      float om = __shfl_xor(gm, off);
      int oi = __shfl_xor(gi, off);
      if (om > gm || (om == gm && oi < gi)) { gm = om; gi = oi; }
    }
    float term = cv ? s * __expf(m - gm) : 0.0f;
#pragma unroll
    for (int off = 1; off < 64; off <<= 1) term += __shfl_xor(term, off);
    if (lane == 0) {
      toks[wv] = gi;
      if (jt == 0) {
        scores[row] -= logf(term);      // += max - logsumexp
        tok_seq[step * BB + row] = gi;  // seq column `step`
      }
    }
  }
  __syncthreads();
  if (step == TSTEPS) return;

  // ---- stage x = relu(emb[tok]) and h_prev ----
  for (int i = tid; i < 4 * EE; i += 256) {
    const int r = i >> 8, c = i & (EE - 1);
    const float e = emb[(size_t)toks[r] * EE + c];
    xs[r][c] = e > 0.0f ? e : 0.0f;
  }
  for (int i = tid; i < 4 * HH; i += 256) {
    const int r = i >> 9, c = i & (HH - 1);
    hsm[r][c] = hin[(r0 + r) * HH + c];
  }
  __syncthreads();

  const int jh = tid & 31, kq = tid >> 5;  // 32 cols x 8 k-slices
  const int j = j0 + jh;
  float ai[3][4], ah[3][4];
#pragma unroll
  for (int g = 0; g < 3; ++g)
#pragma unroll
    for (int r = 0; r < 4; ++r) { ai[g][r] = 0.0f; ah[g][r] = 0.0f; }

  // x-dots: k in [kq*32, kq*32+32)
#pragma unroll 2
  for (int q = 0; q < 8; ++q) {
    const int k4 = kq * 32 + q * 4;
    float4 xr[4];
#pragma unroll
    for (int r = 0; r < 4; ++r) xr[r] = *(const float4*)&xs[r][k4];
#pragma unroll
    for (int g = 0; g < 3; ++g) {
      const float4 w = *(const float4*)&W_ih[(size_t)(g * HH + j) * EE + k4];
#pragma unroll
      for (int r = 0; r < 4; ++r) {
        ai[g][r] = fmaf(xr[r].x, w.x, ai[g][r]);
        ai[g][r] = fmaf(xr[r].y, w.y, ai[g][r]);
        ai[g][r] = fmaf(xr[r].z, w.z, ai[g][r]);
        ai[g][r] = fmaf(xr[r].w, w.w, ai[g][r]);
      }
    }
  }
  // h-dots: k in [kq*64, kq*64+64)
#pragma unroll 2
  for (int q = 0; q < 16; ++q) {
    const int k4 = kq * 64 + q * 4;
    float4 hr[4];
#pragma unroll
    for (int r = 0; r < 4; ++r) hr[r] = *(const float4*)&hsm[r][k4];
#pragma unroll
    for (int g = 0; g < 3; ++g) {
      const float4 w = *(const float4*)&W_hh[(size_t)(g * HH + j) * HH + k4];
#pragma unroll
      for (int r = 0; r < 4; ++r) {
        ah[g][r] = fmaf(hr[r].x, w.x, ah[g][r]);
        ah[g][r] = fmaf(hr[r].y, w.y, ah[g][r]);
        ah[g][r] = fmaf(hr[r].z, w.z, ah[g][r]);
        ah[g][r] = fmaf(hr[r].w, w.w, ah[g][r]);
      }
    }
  }
  // stash partials: gpart[c][kq*34 + jh]
  {
    const int base = kq * 34 + jh;
#pragma unroll
    for (int g = 0; g < 3; ++g)
#pragma unroll
      for (int r = 0; r < 4; ++r) {
        gpart[(g * 4 + r) * 272 + base] = ai[g][r];
        gpart[(12 + g * 4 + r) * 272 + base] = ah[g][r];
      }
  }
  __syncthreads();

  // ---- reduce + gate math: 128 threads = (r 0..3, jh2 0..31) ----
  if (tid < 128) {
    const int r = tid >> 5, jh2 = tid & 31;
    const int j2 = j0 + jh2;
    float g6[6];
#pragma unroll
    for (int c = 0; c < 6; ++c) {
      const int cc = (c < 3) ? (c * 4 + r) : (12 + (c - 3) * 4 + r);
      float s = 0.0f;
#pragma unroll
      for (int q = 0; q < 8; ++q) s += gpart[cc * 272 + q * 34 + jh2];
      g6[c] = s;
    }
    const float ir = g6[0] + b_ih[j2];
    const float iz = g6[1] + b_ih[HH + j2];
    const float in_ = g6[2] + b_ih[2 * HH + j2];
    const float hr_ = g6[3] + b_hh[j2];
    const float hz = g6[4] + b_hh[HH + j2];
    const float hn = g6[5] + b_hh[2 * HH + j2];
    const float rr = 1.0f / (1.0f + expf(-(ir + hr_)));
    const float zz = 1.0f / (1.0f + expf(-(iz + hz)));
    const float nn = tanhf(in_ + rr * hn);
    hout[(r0 + r) * HH + j2] = (1.0f - zz) * nn + zz * hsm[r][j2];
  }
}

// ---------------------------------------------------------------------------
// Epilogue: scatter one-hots, replicate h x3 and scores x3.
// ---------------------------------------------------------------------------
__global__ __launch_bounds__(256) void k_epilogue(
    const int* __restrict__ tok_seq, const float* __restrict__ hfin,
    const float* __restrict__ scores, float* __restrict__ out) {
  const int idx = blockIdx.x * 256 + threadIdx.x;
  if (idx < BB * (TSTEPS + 1)) {
    const int b = idx / (TSTEPS + 1), t = idx % (TSTEPS + 1);
    out[(size_t)b * ((TSTEPS + 1) * VV) + (size_t)t * VV + tok_seq[t * BB + b]] = 1.0f;
  } else if (idx < 1056 + H_ELEMS) {
    const int i = idx - 1056;
    const int b = i / (3 * HH), j = i % HH;
    out[DEC_ELEMS + i] = hfin[b * HH + j];
  } else if (idx < 1056 + H_ELEMS + BB * 3) {
    const int i = idx - 1056 - H_ELEMS;
    out[DEC_ELEMS + H_ELEMS + i] = scores[i / 3];
  }
}

// ---------------------------------------------------------------------------
extern "C" void kernel_launch(void* const* d_in, const int* in_sizes, int n_in,
                              void* d_out, int out_size, void* d_ws, size_t ws_size,
                              hipStream_t stream) {
  const float* enc_h = (const float*)d_in[1];
  const float* emb   = (const float*)d_in[2];
  const float* W_ih  = (const float*)d_in[3];
  const float* W_hh  = (const float*)d_in[4];
  const float* b_ih  = (const float*)d_in[5];
  const float* b_hh  = (const float*)d_in[6];
  const float* W_out = (const float*)d_in[7];
  const float* b_out = (const float*)d_in[8];
  float* out = (float*)d_out;

  // workspace layout (floats)
  float* ws = (float*)d_ws;
  float* Wt_out  = ws;                       // 16,384,000
  float* hb0     = Wt_out + 16384000;        // 16,384
  float* hb1     = hb0 + BB * HH;            // 16,384
  float* pm      = hb1 + BB * HH;            // 1,024
  float* ps      = pm + BB * NCHK;           // 1,024
  float* scores  = ps + BB * NCHK;           // 32
  int*   pidx    = (int*)(scores + BB);      // 1,024
  int*   tok_seq = pidx + BB * NCHK;         // 1,056
  float* lpart   = (float*)(tok_seq + BB * (TSTEPS + 1));  // nkc*32*32000

  // pick split-K factor by available workspace (82.1 / 73.9 / 69.8 MB)
  const size_t fixed = 16384000 + 2 * BB * HH + 2 * BB * NCHK + BB +
                       BB * NCHK + BB * (TSTEPS + 1);
  int nkc = 4;
  if (ws_size < (fixed + 4ull * BB * VV) * 4) nkc = 2;
  if (ws_size < (fixed + 2ull * BB * VV) * 4) nkc = 1;
  const int klen = HH / nkc;
  const size_t hs_bytes = (size_t)32 * klen * sizeof(float);

  hipMemsetAsync(d_out, 0, (size_t)out_size * sizeof(float), stream);
  k_transpose_out<<<dim3(1000, 16), 256, 0, stream>>>(W_out, Wt_out);
  k_init<<<64, 256, 0, stream>>>(enc_h, hb0, scores, tok_seq);

  for (int t = 0; t < TSTEPS; ++t) {
    float* hin  = (t & 1) ? hb1 : hb0;
    float* hout = (t & 1) ? hb0 : hb1;
    k_gru<<<128, 256, 0, stream>>>(t, emb, W_ih, W_hh, b_ih, b_hh,
                                   hin, hout, pm, ps, pidx, scores, tok_seq);
    k_gemv<<<dim3(63, nkc), 256, hs_bytes, stream>>>(Wt_out, hout, lpart, klen);
    k_combine<<<dim3(NCHK, BB), 256, 0, stream>>>(lpart, b_out, pm, ps, pidx, nkc);
  }
  // final selection: seq col 32 + last score term
  k_gru<<<128, 256, 0, stream>>>(TSTEPS, emb, W_ih, W_hh, b_ih, b_hh,
                                 hb0, hb1, pm, ps, pidx, scores, tok_seq);
  // final h lives in hb0 (t=31 odd: hout=hb0)
  k_epilogue<<<197, 256, 0, stream>>>(tok_seq, hb0, scores, out);
}